// Round 1
// baseline (496.822 us; speedup 1.0000x reference)
//
#include <hip/hip_runtime.h>
#include <math.h>

#define KNBR 20
#define FDIM 384   // D + DT + DE
#define EDIM 128

// ---------------------------------------------------------------------------
// Stage A: nf_sum[row][0:384] = sum over k of masked neighbor features
//   [0,128)   : neighbor embedding (2*memory[nid]  OR  emb_seq[(row*K+k)])
//   [128,256) : cos((ts - etime)*w + b)
//   [256,384) : edge_features[eidx]
// mask: nid == 0 -> contributes nothing
// ---------------------------------------------------------------------------
__global__ __launch_bounds__(384) void nf_sum_kernel(
    const float* __restrict__ memory,        // [N_NODES,128]
    const float* __restrict__ edge_features, // [N_EDGES,128]
    const float* __restrict__ time_w,        // [128]
    const float* __restrict__ time_b,        // [128]
    const float* __restrict__ timestamps,    // [N]
    int ts_div,                              // ts index = row / ts_div
    const int* __restrict__ nbr,             // [B,K]
    const int* __restrict__ eidx,            // [B,K]
    const float* __restrict__ etime,         // [B,K]
    const float* __restrict__ emb_seq,       // nullable: [B*K,128] (layer-2 mode)
    float* __restrict__ nf_sum)              // [B,384]
{
    const int row = blockIdx.x;
    const int d = threadIdx.x;
    const float ts = timestamps[row / ts_div];

    float w = 0.f, bb = 0.f;
    if (d >= 128 && d < 256) { w = time_w[d - 128]; bb = time_b[d - 128]; }

    float acc = 0.f;
    for (int k = 0; k < KNBR; ++k) {
        const int nid = nbr[row * KNBR + k];
        if (nid == 0) continue;  // masked neighbor: whole nf row zeroed
        if (d < 128) {
            if (emb_seq)
                acc += emb_seq[(row * KNBR + k) * EDIM + d];
            else
                acc += 2.f * memory[(size_t)nid * EDIM + d];
        } else if (d < 256) {
            const float dt = ts - etime[row * KNBR + k];
            acc += cosf(fmaf(dt, w, bb));
        } else {
            const int e = eidx[row * KNBR + k];
            acc += edge_features[(size_t)e * EDIM + (d - 256)];
        }
    }
    nf_sum[(size_t)row * FDIM + d] = acc;
}

// ---------------------------------------------------------------------------
// Stage B: s = relu(nf_sum @ W + bias_scale * bias)   [B,384]x[384,128]
// 16 rows per block, 128 threads (one per output col), outer-product loop.
// ---------------------------------------------------------------------------
__global__ __launch_bounds__(128) void gemm_relu_kernel(
    const float* __restrict__ nf,   // [B,384]
    const float* __restrict__ W,    // [384,128]
    const float* __restrict__ bias, // [128]
    float bias_scale,
    float* __restrict__ out)        // [B,128]
{
    __shared__ float lds[16 * FDIM];
    const int row0 = blockIdx.x * 16;
    const int tid = threadIdx.x;

    const float* src = nf + (size_t)row0 * FDIM;
    for (int i = tid; i < 16 * FDIM; i += 128) lds[i] = src[i];
    __syncthreads();

    float acc[16];
#pragma unroll
    for (int r = 0; r < 16; ++r) acc[r] = 0.f;

    const int col = tid;
    for (int f = 0; f < FDIM; f += 4) {
        const float w0 = W[(f + 0) * 128 + col];
        const float w1 = W[(f + 1) * 128 + col];
        const float w2 = W[(f + 2) * 128 + col];
        const float w3 = W[(f + 3) * 128 + col];
#pragma unroll
        for (int r = 0; r < 16; ++r) {
            const float4 v = *reinterpret_cast<const float4*>(&lds[r * FDIM + f]);
            acc[r] = fmaf(v.x, w0, fmaf(v.y, w1, fmaf(v.z, w2, fmaf(v.w, w3, acc[r]))));
        }
    }

    const float b = bias[col] * bias_scale;
#pragma unroll
    for (int r = 0; r < 16; ++r) {
        out[(size_t)(row0 + r) * 128 + col] = fmaxf(acc[r] + b, 0.f);
    }
}

// ---------------------------------------------------------------------------
// Stage C: out = concat([s, mid, cos(time_b)]) @ W + bias  (no relu)
//   mid = 2*memory[mid_idx[row]]  if mid_idx != null, else mid[row]
// ---------------------------------------------------------------------------
__global__ __launch_bounds__(128) void cat_gemm_kernel(
    const float* __restrict__ s,       // [B,128]
    const float* __restrict__ mid,     // [B,128] or null
    const int* __restrict__ mid_idx,   // [B] or null
    const float* __restrict__ memory,  // [N_NODES,128]
    const float* __restrict__ time_b,  // [128]
    const float* __restrict__ W,       // [384,128]
    const float* __restrict__ bias,    // [128]
    float* __restrict__ out)           // [B,128]
{
    __shared__ float lds[16 * FDIM];
    const int row0 = blockIdx.x * 16;
    const int tid = threadIdx.x;

    const float ones = cosf(time_b[tid]);  // == 1.0 for zero bias
    for (int r = 0; r < 16; ++r) {
        const int row = row0 + r;
        lds[r * FDIM + tid] = s[(size_t)row * 128 + tid];
        float m;
        if (mid_idx) {
            const int nid = mid_idx[row];
            m = 2.f * memory[(size_t)nid * EDIM + tid];
        } else {
            m = mid[(size_t)row * 128 + tid];
        }
        lds[r * FDIM + 128 + tid] = m;
        lds[r * FDIM + 256 + tid] = ones;
    }
    __syncthreads();

    float acc[16];
#pragma unroll
    for (int r = 0; r < 16; ++r) acc[r] = 0.f;

    const int col = tid;
    for (int f = 0; f < FDIM; f += 4) {
        const float w0 = W[(f + 0) * 128 + col];
        const float w1 = W[(f + 1) * 128 + col];
        const float w2 = W[(f + 2) * 128 + col];
        const float w3 = W[(f + 3) * 128 + col];
#pragma unroll
        for (int r = 0; r < 16; ++r) {
            const float4 v = *reinterpret_cast<const float4*>(&lds[r * FDIM + f]);
            acc[r] = fmaf(v.x, w0, fmaf(v.y, w1, fmaf(v.z, w2, fmaf(v.w, w3, acc[r]))));
        }
    }

    const float b = bias[col];
#pragma unroll
    for (int r = 0; r < 16; ++r) {
        out[(size_t)(row0 + r) * 128 + col] = acc[r] + b;
    }
}

// ---------------------------------------------------------------------------
extern "C" void kernel_launch(void* const* d_in, const int* in_sizes, int n_in,
                              void* d_out, int out_size, void* d_ws, size_t ws_size,
                              hipStream_t stream) {
    const float* memory        = (const float*)d_in[0];   // [100000,128]
    const float* edge_features = (const float*)d_in[1];   // [1000000,128]
    const float* timestamps    = (const float*)d_in[2];   // [1024]
    const float* time_w        = (const float*)d_in[3];   // [128]
    const float* time_b        = (const float*)d_in[4];   // [128]
    const float* W1            = (const float*)d_in[5];   // [2,384,128]
    const float* b1            = (const float*)d_in[6];   // [2,128]
    const float* W2            = (const float*)d_in[7];   // [2,384,128]
    const float* b2            = (const float*)d_in[8];   // [2,128]
    const int*   source_nodes  = (const int*)d_in[9];     // [1024]
    const int*   nbr1          = (const int*)d_in[10];    // [1024,20]
    const int*   eidx1         = (const int*)d_in[11];    // [1024,20]
    const float* etime1        = (const float*)d_in[12];  // [1024,20]
    const int*   nbr2          = (const int*)d_in[13];    // [20480,20]
    const int*   eidx2         = (const int*)d_in[14];    // [20480,20]
    const float* etime2        = (const float*)d_in[15];  // [20480,20]

    const int N = 1024;
    const int NK = N * KNBR;  // 20480

    // workspace layout (floats), with lifetime-based aliasing
    float* ws = (float*)d_ws;
    float* nf2   = ws;                       // 20480*384   [dead after step 4]
    float* s2    = nf2 + (size_t)NK * FDIM;  // 20480*128   [dead after step 6]
    float* nf1   = s2 + (size_t)NK * 128;    // 1024*384    [dead after step 3]
    float* s1    = nf1 + (size_t)N * FDIM;   // 1024*128    [dead after step 5]
    float* conv  = s1 + (size_t)N * 128;     // 1024*128    [live to the end]
    float* embL1 = nf2;                      // 20480*128   reuses nf2 slot
    float* nfl2  = nf1;                      // 1024*384    reuses nf1 slot
    float* sl2   = s1;                       // 1024*128    reuses s1 slot

    const float* W1_0 = W1;               const float* W1_1 = W1 + 384 * 128;
    const float* b1_0 = b1;               const float* b1_1 = b1 + 128;
    const float* W2_0 = W2;               const float* W2_1 = W2 + 384 * 128;
    const float* b2_0 = b2;               const float* b2_1 = b2 + 128;

    // 1. layer1 nf-sum, source batch
    nf_sum_kernel<<<N, 384, 0, stream>>>(memory, edge_features, time_w, time_b,
                                         timestamps, 1, nbr1, eidx1, etime1,
                                         nullptr, nf1);
    // 2. layer1 nf-sum, flattened 1-hop neighbors (ts index = row/20)
    nf_sum_kernel<<<NK, 384, 0, stream>>>(memory, edge_features, time_w, time_b,
                                          timestamps, KNBR, nbr2, eidx2, etime2,
                                          nullptr, nf2);
    // 3. s1 = relu(nf1 @ W1[0] + 20*b1[0])
    gemm_relu_kernel<<<N / 16, 128, 0, stream>>>(nf1, W1_0, b1_0, (float)KNBR, s1);
    // 4. s2 = relu(nf2 @ W1[0] + 20*b1[0])
    gemm_relu_kernel<<<NK / 16, 128, 0, stream>>>(nf2, W1_0, b1_0, (float)KNBR, s2);
    // 5. conv = concat([s1, 2*memory[src], ones]) @ W2[0] + b2[0]
    cat_gemm_kernel<<<N / 16, 128, 0, stream>>>(s1, nullptr, source_nodes, memory,
                                                time_b, W2_0, b2_0, conv);
    // 6. embL1 = concat([s2, 2*memory[nbr1.flat], ones]) @ W2[0] + b2[0]
    cat_gemm_kernel<<<NK / 16, 128, 0, stream>>>(s2, nullptr, nbr1, memory,
                                                 time_b, W2_0, b2_0, embL1);
    // 7. layer2 nf-sum (neighbor emb from embL1, mask from nbr1)
    nf_sum_kernel<<<N, 384, 0, stream>>>(memory, edge_features, time_w, time_b,
                                         timestamps, 1, nbr1, eidx1, etime1,
                                         embL1, nfl2);
    // 8. sl2 = relu(nfl2 @ W1[1] + 20*b1[1])
    gemm_relu_kernel<<<N / 16, 128, 0, stream>>>(nfl2, W1_1, b1_1, (float)KNBR, sl2);
    // 9. out = concat([sl2, conv, ones]) @ W2[1] + b2[1]
    cat_gemm_kernel<<<N / 16, 128, 0, stream>>>(sl2, conv, nullptr, memory,
                                                time_b, W2_1, b2_1, (float*)d_out);
}

// Round 2
// 215.618 us; speedup vs baseline: 2.3042x; 2.3042x over previous
//
#include <hip/hip_runtime.h>
#include <math.h>

#define KNBR 20
#define NFK 384
#define NFPAD 392     // +8 bf16 pad -> row stride 784B, 2-way banks (free)
#define CATK 256      // "ones" block folded into bias2_eff
#define CATPAD 264
#define KS1 12        // 384/32 k-steps
#define KS2 8         // 256/32 k-steps
#define WF1_PER_LAYER (8 * KS1 * 64 * 8)   // 49152
#define WF2_PER_LAYER (8 * KS2 * 64 * 8)   // 32768

typedef __attribute__((ext_vector_type(8))) short short8;
typedef __attribute__((ext_vector_type(4))) float f32x4;

__device__ __forceinline__ unsigned short f2bf(float f) {
    unsigned u = __float_as_uint(f);
    unsigned r = (u + 0x7FFFu + ((u >> 16) & 1u)) >> 16;  // RNE
    return (unsigned short)r;
}

__device__ __forceinline__ float fast_cos(float ang) {
    // cos(ang) for |ang| up to ~1e4 rad: reduce in revolutions, then __cosf on [-pi,pi]
    float rev = ang * 0.15915494309189535f;
    rev -= floorf(rev);  // [0,1)
    return -__cosf(6.283185307179586f * (rev - 0.5f));
}

// ---------------------------------------------------------------------------
// One-time (per call) weight repack: W -> MFMA B-fragment order, bf16.
// Consumer reads: wf[(((ct*KS + ks)*64 + lane)*8 + j]
//   k = ks*32 + (lane>>4)*8 + j, col = ct*16 + (lane&15)
// Also bias2_eff[l][col] = b2[l][col] + sum_f cos(time_b[f]) * W2[l][256+f][col]
// ---------------------------------------------------------------------------
__global__ __launch_bounds__(256) void setup_kernel(
    const float* __restrict__ W1, const float* __restrict__ W2,
    const float* __restrict__ b2, const float* __restrict__ time_b,
    unsigned short* __restrict__ wf1, unsigned short* __restrict__ wf2,
    float* __restrict__ bias2_eff)
{
    const int id = blockIdx.x * 256 + threadIdx.x;
    const int N1 = 2 * WF1_PER_LAYER;   // 98304
    const int N2 = 2 * WF2_PER_LAYER;   // 65536
    if (id < N1) {
        const int layer = id / WF1_PER_LAYER;
        const int idl = id % WF1_PER_LAYER;
        const int ct = idl / (KS1 * 512);
        const int ks = (idl / 512) % KS1;
        const int l = (idl >> 3) & 63;
        const int j = idl & 7;
        const int k = ks * 32 + (l >> 4) * 8 + j;
        const int col = ct * 16 + (l & 15);
        wf1[id] = f2bf(W1[(size_t)layer * NFK * 128 + k * 128 + col]);
    } else if (id < N1 + N2) {
        const int id2 = id - N1;
        const int layer = id2 / WF2_PER_LAYER;
        const int idl = id2 % WF2_PER_LAYER;
        const int ct = idl / (KS2 * 512);
        const int ks = (idl / 512) % KS2;
        const int l = (idl >> 3) & 63;
        const int j = idl & 7;
        const int k = ks * 32 + (l >> 4) * 8 + j;
        const int col = ct * 16 + (l & 15);
        wf2[id2] = f2bf(W2[(size_t)layer * NFK * 128 + k * 128 + col]);
    } else if (id < N1 + N2 + 256) {
        const int id3 = id - N1 - N2;
        const int layer = id3 / 128, col = id3 % 128;
        float s = b2[layer * 128 + col];
        for (int f = 0; f < 128; ++f)
            s += cosf(time_b[f]) * W2[(size_t)layer * NFK * 128 + (256 + f) * 128 + col];
        bias2_eff[id3] = s;
    }
}

// ---------------------------------------------------------------------------
// Fused per-row MLP: gather+cos -> nf tile (bf16 LDS) -> MFMA GEMM1+relu
//   -> cat tile -> MFMA GEMM2 (+folded ones-bias) -> out
// 16 rows / block, 128 threads (2 waves; wave w handles col-tiles w*4..w*4+3)
// ---------------------------------------------------------------------------
template<bool L2MODE>
__global__ __launch_bounds__(128) void fused_mlp(
    const float* __restrict__ memory,
    const float* __restrict__ edge_features,
    const float* __restrict__ timestamps,
    const float* __restrict__ time_w,
    const float* __restrict__ time_b,
    const int* __restrict__ source_nodes,
    const int* __restrict__ nbr1, const int* __restrict__ eidx1, const float* __restrict__ etime1,
    const int* __restrict__ nbr2, const int* __restrict__ eidx2, const float* __restrict__ etime2,
    const float* __restrict__ emb_all,       // L2: [21504,128] = [conv ; embL1]
    const unsigned short* __restrict__ wf1,  // this layer's W1 frags
    const unsigned short* __restrict__ wf2,  // this layer's W2 frags (k<256)
    const float* __restrict__ b1l,           // this layer's b1 [128]
    const float* __restrict__ bias2l,        // this layer's bias2_eff [128]
    float* __restrict__ out)
{
    __shared__ alignas(16) unsigned short nf[16][NFPAD];
    __shared__ alignas(16) unsigned short cat[16][CATPAD];

    const int tid = threadIdx.x;
    const int lane = tid & 63;
    const int wv = tid >> 6;
    const int row0 = blockIdx.x * 16;

    const float wt = time_w[tid];
    const float bt = time_b[tid];

    for (int r = 0; r < 16; ++r) {
        const int row = row0 + r;
        const int* nbrp; const int* eixp; const float* etmp; float ts;
        const float* embp = nullptr; float midv;
        if (L2MODE) {
            ts = timestamps[row];
            nbrp = nbr1 + row * KNBR; eixp = eidx1 + row * KNBR; etmp = etime1 + row * KNBR;
            embp = emb_all + (size_t)(1024 + row * KNBR) * 128;
            midv = emb_all[(size_t)row * 128 + tid];            // conv row
        } else if (row0 < 1024) {
            ts = timestamps[row];
            nbrp = nbr1 + row * KNBR; eixp = eidx1 + row * KNBR; etmp = etime1 + row * KNBR;
            const int mid_nid = source_nodes[row];
            midv = 2.f * memory[(size_t)mid_nid * 128 + tid];
        } else {
            const int i = row - 1024;
            ts = timestamps[i / KNBR];
            nbrp = nbr2 + i * KNBR; eixp = eidx2 + i * KNBR; etmp = etime2 + i * KNBR;
            const int mid_nid = nbr1[i];
            midv = 2.f * memory[(size_t)mid_nid * 128 + tid];
        }
        cat[r][128 + tid] = f2bf(midv);

        float accm = 0.f, accc = 0.f, acce = 0.f;
#pragma unroll
        for (int k = 0; k < KNBR; ++k) {
            const int nid = nbrp[k];
            const int eid = eixp[k];
            const float live = (nid != 0) ? 1.f : 0.f;
            float m;
            if (L2MODE) m = embp[k * 128 + tid];
            else        m = 2.f * memory[(size_t)nid * 128 + tid];
            const float e = edge_features[(size_t)eid * 128 + tid];
            const float c = fast_cos(fmaf(ts - etmp[k], wt, bt));
            accm += live * m;
            accc += live * c;
            acce += live * e;
        }
        nf[r][tid]       = f2bf(accm);
        nf[r][128 + tid] = f2bf(accc);
        nf[r][256 + tid] = f2bf(acce);
    }
    __syncthreads();

    const int lo = lane & 15, hi = lane >> 4;

    // ---- GEMM1: s = relu(nf @ W1 + 20*b1) ----
    f32x4 acc[4];
#pragma unroll
    for (int c = 0; c < 4; ++c) acc[c] = (f32x4){0.f, 0.f, 0.f, 0.f};
    for (int ks = 0; ks < KS1; ++ks) {
        const short8 a = *reinterpret_cast<const short8*>(&nf[lo][ks * 32 + hi * 8]);
#pragma unroll
        for (int c = 0; c < 4; ++c) {
            const int ct = wv * 4 + c;
            const short8 b = *reinterpret_cast<const short8*>(
                &wf1[(((size_t)ct * KS1 + ks) * 64 + lane) * 8]);
            acc[c] = __builtin_amdgcn_mfma_f32_16x16x32_bf16(a, b, acc[c], 0, 0, 0);
        }
    }
#pragma unroll
    for (int c = 0; c < 4; ++c) {
        const int col = (wv * 4 + c) * 16 + lo;
        const float bv = 20.f * b1l[col];
#pragma unroll
        for (int j = 0; j < 4; ++j) {
            const int r = hi * 4 + j;              // C layout: col=lane&15, row=(lane>>4)*4+j
            cat[r][col] = f2bf(fmaxf(acc[c][j] + bv, 0.f));
        }
    }
    __syncthreads();

    // ---- GEMM2: out = cat @ W2[0:256] + bias2_eff ----
#pragma unroll
    for (int c = 0; c < 4; ++c) acc[c] = (f32x4){0.f, 0.f, 0.f, 0.f};
    for (int ks = 0; ks < KS2; ++ks) {
        const short8 a = *reinterpret_cast<const short8*>(&cat[lo][ks * 32 + hi * 8]);
#pragma unroll
        for (int c = 0; c < 4; ++c) {
            const int ct = wv * 4 + c;
            const short8 b = *reinterpret_cast<const short8*>(
                &wf2[(((size_t)ct * KS2 + ks) * 64 + lane) * 8]);
            acc[c] = __builtin_amdgcn_mfma_f32_16x16x32_bf16(a, b, acc[c], 0, 0, 0);
        }
    }
#pragma unroll
    for (int c = 0; c < 4; ++c) {
        const int col = (wv * 4 + c) * 16 + lo;
        const float bv = bias2l[col];
#pragma unroll
        for (int j = 0; j < 4; ++j) {
            const int r = hi * 4 + j;
            out[(size_t)(row0 + r) * 128 + col] = acc[c][j] + bv;
        }
    }
}

// ---------------------------------------------------------------------------
extern "C" void kernel_launch(void* const* d_in, const int* in_sizes, int n_in,
                              void* d_out, int out_size, void* d_ws, size_t ws_size,
                              hipStream_t stream) {
    const float* memory        = (const float*)d_in[0];
    const float* edge_features = (const float*)d_in[1];
    const float* timestamps    = (const float*)d_in[2];
    const float* time_w        = (const float*)d_in[3];
    const float* time_b        = (const float*)d_in[4];
    const float* W1            = (const float*)d_in[5];
    const float* b1            = (const float*)d_in[6];
    const float* W2            = (const float*)d_in[7];
    const float* b2            = (const float*)d_in[8];
    const int*   source_nodes  = (const int*)d_in[9];
    const int*   nbr1          = (const int*)d_in[10];
    const int*   eidx1         = (const int*)d_in[11];
    const float* etime1        = (const float*)d_in[12];
    const int*   nbr2          = (const int*)d_in[13];
    const int*   eidx2         = (const int*)d_in[14];
    const float* etime2        = (const float*)d_in[15];

    const int N = 1024;
    const int NROWS = N + N * KNBR;  // 21504

    // ws layout: emb_all [21504*128 f32] | bias2_eff [256 f32] | wf1 [98304 u16] | wf2 [65536 u16]
    float* emb_all = (float*)d_ws;
    float* bias2_eff = emb_all + (size_t)NROWS * 128;
    unsigned short* wf1 = (unsigned short*)(bias2_eff + 256);
    unsigned short* wf2 = wf1 + 2 * WF1_PER_LAYER;

    // 1. repack weights + fold ones-block into bias
    setup_kernel<<<641, 256, 0, stream>>>(W1, W2, b2, time_b, wf1, wf2, bias2_eff);

    // 2. layer-1 fused MLP over [source batch (1024) ; flattened 1-hop (20480)]
    fused_mlp<false><<<NROWS / 16, 128, 0, stream>>>(
        memory, edge_features, timestamps, time_w, time_b, source_nodes,
        nbr1, eidx1, etime1, nbr2, eidx2, etime2,
        emb_all, wf1, wf2, b1, bias2_eff, emb_all);

    // 3. layer-2 fused MLP over source batch, reading emb_all
    fused_mlp<true><<<N / 16, 128, 0, stream>>>(
        memory, edge_features, timestamps, time_w, time_b, source_nodes,
        nbr1, eidx1, etime1, nbr2, eidx2, etime2,
        emb_all, wf1 + WF1_PER_LAYER, wf2 + WF2_PER_LAYER,
        b1 + 128, bias2_eff + 128, (float*)d_out);
}

// Round 3
// 137.419 us; speedup vs baseline: 3.6154x; 1.5691x over previous
//
#include <hip/hip_runtime.h>
#include <hip/hip_bf16.h>
#include <math.h>

#define KNBR 20
#define NFK 384
#define NFPAD 392     // bf16 pad -> row stride 784B (16B-aligned), minor bank aliasing
#define CATPAD 264
#define KS1 12        // 384/32 k-steps
#define KS2 8         // 256/32 k-steps ("ones" block folded into bias2_eff)
#define WF1_PER_LAYER (8 * KS1 * 64 * 8)   // 49152
#define WF2_PER_LAYER (8 * KS2 * 64 * 8)   // 32768
#define INV2PI 0.15915494309189535f

typedef __attribute__((ext_vector_type(8))) short short8;
typedef __attribute__((ext_vector_type(4))) float f32x4;

__device__ __forceinline__ unsigned short f2bf(float f) {
    unsigned u = __float_as_uint(f);
    unsigned r = (u + 0x7FFFu + ((u >> 16) & 1u)) >> 16;  // RNE
    return (unsigned short)r;
}

__device__ __forceinline__ float fract_(float x) {
#if __has_builtin(__builtin_amdgcn_fractf)
    return __builtin_amdgcn_fractf(x);
#else
    return x - floorf(x);
#endif
}
__device__ __forceinline__ float cos_rev(float rev) {  // cos(2*pi*rev), any rev
#if __has_builtin(__builtin_amdgcn_cosf)
    return __builtin_amdgcn_cosf(fract_(rev));
#else
    float o, r = fract_(rev);
    asm("v_cos_f32 %0, %1" : "=v"(o) : "v"(r));
    return o;
#endif
}

// ---------------------------------------------------------------------------
// One-time weight repack: W -> MFMA B-fragment order (bf16) + ones-bias fold.
// Consumer reads: wf[(((ct*KS + ks)*64 + lane)*8 + j]
//   k = ks*32 + (lane>>4)*8 + j, col = ct*16 + (lane&15)
// ---------------------------------------------------------------------------
__global__ __launch_bounds__(256) void setup_kernel(
    const float* __restrict__ W1, const float* __restrict__ W2,
    const float* __restrict__ b2, const float* __restrict__ time_b,
    unsigned short* __restrict__ wf1, unsigned short* __restrict__ wf2,
    float* __restrict__ bias2_eff)
{
    const int id = blockIdx.x * 256 + threadIdx.x;
    const int N1 = 2 * WF1_PER_LAYER;
    const int N2 = 2 * WF2_PER_LAYER;
    if (id < N1) {
        const int layer = id / WF1_PER_LAYER;
        const int idl = id % WF1_PER_LAYER;
        const int ct = idl / (KS1 * 512);
        const int ks = (idl / 512) % KS1;
        const int l = (idl >> 3) & 63;
        const int j = idl & 7;
        const int k = ks * 32 + (l >> 4) * 8 + j;
        const int col = ct * 16 + (l & 15);
        wf1[id] = f2bf(W1[(size_t)layer * NFK * 128 + k * 128 + col]);
    } else if (id < N1 + N2) {
        const int id2 = id - N1;
        const int layer = id2 / WF2_PER_LAYER;
        const int idl = id2 % WF2_PER_LAYER;
        const int ct = idl / (KS2 * 512);
        const int ks = (idl / 512) % KS2;
        const int l = (idl >> 3) & 63;
        const int j = idl & 7;
        const int k = ks * 32 + (l >> 4) * 8 + j;
        const int col = ct * 16 + (l & 15);
        wf2[id2] = f2bf(W2[(size_t)layer * NFK * 128 + k * 128 + col]);
    } else if (id < N1 + N2 + 256) {
        const int id3 = id - N1 - N2;
        const int layer = id3 / 128, col = id3 % 128;
        float s = b2[layer * 128 + col];
        for (int f = 0; f < 128; ++f)
            s += cosf(time_b[f]) * W2[(size_t)layer * NFK * 128 + (256 + f) * 128 + col];
        bias2_eff[id3] = s;
    }
}

// ---------------------------------------------------------------------------
// Fused per-row MLP, 256 threads (4 waves), RPB rows per block.
// Staging: half-wave hw (32 lanes, float4 per lane = 512B row gather) owns
// RPB/8 rows; cos merged into the gather loop (4 per lane per k).
// GEMM: wave wv handles col-tiles {wv*2, wv*2+1}.
// ---------------------------------------------------------------------------
template<bool L2MODE, int RPB>
__global__ __launch_bounds__(256) void fused_mlp(
    const float* __restrict__ memory,
    const float* __restrict__ edge_features,
    const float* __restrict__ timestamps,
    const float* __restrict__ time_w,
    const float* __restrict__ time_b,
    const int* __restrict__ source_nodes,
    const int* __restrict__ nbr1, const int* __restrict__ eidx1, const float* __restrict__ etime1,
    const int* __restrict__ nbr2, const int* __restrict__ eidx2, const float* __restrict__ etime2,
    const float* __restrict__ emb_all,       // [21504,128] = [conv ; embL1]
    const unsigned short* __restrict__ wf1,
    const unsigned short* __restrict__ wf2,
    const float* __restrict__ b1l,
    const float* __restrict__ bias2l,
    float* __restrict__ out)
{
    __shared__ alignas(16) unsigned short nf[16][NFPAD];
    __shared__ alignas(16) unsigned short cat[16][CATPAD];

    const int tid = threadIdx.x;
    const int row0 = blockIdx.x * RPB;
    const int hw = tid >> 5;         // half-wave id 0..7
    const int l32 = tid & 31;
    const int d4 = l32 * 4;          // this lane's 4 feature dims
    constexpr int RPH = RPB / 8;     // rows per half-wave

    // pre-scaled time consts: cos(dt*w+b) = cos_rev(dt*w' + b')
    const f32x4 wtr = { time_w[d4] * INV2PI, time_w[d4+1] * INV2PI,
                        time_w[d4+2] * INV2PI, time_w[d4+3] * INV2PI };
    const f32x4 btr = { time_b[d4] * INV2PI, time_b[d4+1] * INV2PI,
                        time_b[d4+2] * INV2PI, time_b[d4+3] * INV2PI };

    for (int ri = 0; ri < RPH; ++ri) {
        const int r = hw * RPH + ri;
        const int row = row0 + r;
        const int* nbrp; const int* eixp; const float* etmp; float ts;
        const float* embp = nullptr; const float* midp; float midscale;
        if (L2MODE) {
            ts = timestamps[row];
            nbrp = nbr1 + row * KNBR; eixp = eidx1 + row * KNBR; etmp = etime1 + row * KNBR;
            embp = emb_all + (size_t)(1024 + row * KNBR) * 128;
            midp = emb_all + (size_t)row * 128; midscale = 1.f;
        } else if (row0 < 1024) {
            ts = timestamps[row];
            nbrp = nbr1 + row * KNBR; eixp = eidx1 + row * KNBR; etmp = etime1 + row * KNBR;
            midp = memory + (size_t)source_nodes[row] * 128; midscale = 2.f;
        } else {
            const int i = row - 1024;
            ts = timestamps[i / KNBR];
            nbrp = nbr2 + i * KNBR; eixp = eidx2 + i * KNBR; etmp = etime2 + i * KNBR;
            midp = memory + (size_t)nbr1[i] * 128; midscale = 2.f;
        }

        f32x4 am = {0.f,0.f,0.f,0.f}, ac = {0.f,0.f,0.f,0.f}, ae = {0.f,0.f,0.f,0.f};
#pragma unroll
        for (int k = 0; k < KNBR; ++k) {
            const int nid = nbrp[k];
            const int eid = eixp[k];
            const float dt = ts - etmp[k];
            const float live = (nid != 0) ? 1.f : 0.f;
            const f32x4 mv = L2MODE
                ? *reinterpret_cast<const f32x4*>(&embp[k * 128 + d4])
                : *reinterpret_cast<const f32x4*>(&memory[(size_t)nid * 128 + d4]);
            const f32x4 ev = *reinterpret_cast<const f32x4*>(&edge_features[(size_t)eid * 128 + d4]);
            am += live * mv;
            ae += live * ev;
            ac.x += live * cos_rev(fmaf(dt, wtr.x, btr.x));
            ac.y += live * cos_rev(fmaf(dt, wtr.y, btr.y));
            ac.z += live * cos_rev(fmaf(dt, wtr.z, btr.z));
            ac.w += live * cos_rev(fmaf(dt, wtr.w, btr.w));
        }
        const float ms = L2MODE ? 1.f : 2.f;
        ushort4 pm = { f2bf(am.x*ms), f2bf(am.y*ms), f2bf(am.z*ms), f2bf(am.w*ms) };
        ushort4 pc = { f2bf(ac.x), f2bf(ac.y), f2bf(ac.z), f2bf(ac.w) };
        ushort4 pe = { f2bf(ae.x), f2bf(ae.y), f2bf(ae.z), f2bf(ae.w) };
        *reinterpret_cast<ushort4*>(&nf[r][d4])       = pm;
        *reinterpret_cast<ushort4*>(&nf[r][128 + d4]) = pc;
        *reinterpret_cast<ushort4*>(&nf[r][256 + d4]) = pe;

        const f32x4 md = *reinterpret_cast<const f32x4*>(&midp[d4]);
        ushort4 pd = { f2bf(md.x*midscale), f2bf(md.y*midscale),
                       f2bf(md.z*midscale), f2bf(md.w*midscale) };
        *reinterpret_cast<ushort4*>(&cat[r][128 + d4]) = pd;
    }
    __syncthreads();

    const int lane = tid & 63;
    const int wv = tid >> 6;
    const int lo = lane & 15, hi = lane >> 4;

    // ---- GEMM1: s = relu(nf @ W1 + 20*b1) ----
    f32x4 acc[2];
    acc[0] = (f32x4){0.f,0.f,0.f,0.f}; acc[1] = (f32x4){0.f,0.f,0.f,0.f};
    for (int ks = 0; ks < KS1; ++ks) {
        const short8 a = *reinterpret_cast<const short8*>(&nf[lo][ks * 32 + hi * 8]);
#pragma unroll
        for (int c = 0; c < 2; ++c) {
            const int ct = wv * 2 + c;
            const short8 b = *reinterpret_cast<const short8*>(
                &wf1[(((size_t)ct * KS1 + ks) * 64 + lane) * 8]);
            acc[c] = __builtin_amdgcn_mfma_f32_16x16x32_bf16(a, b, acc[c], 0, 0, 0);
        }
    }
#pragma unroll
    for (int c = 0; c < 2; ++c) {
        const int col = (wv * 2 + c) * 16 + lo;
        const float bv = 20.f * b1l[col];
#pragma unroll
        for (int j = 0; j < 4; ++j) {
            const int r = hi * 4 + j;              // C layout: col=lane&15, row=(lane>>4)*4+j
            if (RPB == 16 || r < RPB)
                cat[r][col] = f2bf(fmaxf(acc[c][j] + bv, 0.f));
        }
    }
    __syncthreads();

    // ---- GEMM2: out = cat @ W2[0:256] + bias2_eff ----
    acc[0] = (f32x4){0.f,0.f,0.f,0.f}; acc[1] = (f32x4){0.f,0.f,0.f,0.f};
    for (int ks = 0; ks < KS2; ++ks) {
        const short8 a = *reinterpret_cast<const short8*>(&cat[lo][ks * 32 + hi * 8]);
#pragma unroll
        for (int c = 0; c < 2; ++c) {
            const int ct = wv * 2 + c;
            const short8 b = *reinterpret_cast<const short8*>(
                &wf2[(((size_t)ct * KS2 + ks) * 64 + lane) * 8]);
            acc[c] = __builtin_amdgcn_mfma_f32_16x16x32_bf16(a, b, acc[c], 0, 0, 0);
        }
    }
#pragma unroll
    for (int c = 0; c < 2; ++c) {
        const int col = (wv * 2 + c) * 16 + lo;
        const float bv = bias2l[col];
#pragma unroll
        for (int j = 0; j < 4; ++j) {
            const int r = hi * 4 + j;
            if (RPB == 16 || r < RPB)
                out[(size_t)(row0 + r) * 128 + col] = acc[c][j] + bv;
        }
    }
}

// ---------------------------------------------------------------------------
extern "C" void kernel_launch(void* const* d_in, const int* in_sizes, int n_in,
                              void* d_out, int out_size, void* d_ws, size_t ws_size,
                              hipStream_t stream) {
    const float* memory        = (const float*)d_in[0];
    const float* edge_features = (const float*)d_in[1];
    const float* timestamps    = (const float*)d_in[2];
    const float* time_w        = (const float*)d_in[3];
    const float* time_b        = (const float*)d_in[4];
    const float* W1            = (const float*)d_in[5];
    const float* b1            = (const float*)d_in[6];
    const float* W2            = (const float*)d_in[7];
    const float* b2            = (const float*)d_in[8];
    const int*   source_nodes  = (const int*)d_in[9];
    const int*   nbr1          = (const int*)d_in[10];
    const int*   eidx1         = (const int*)d_in[11];
    const float* etime1        = (const float*)d_in[12];
    const int*   nbr2          = (const int*)d_in[13];
    const int*   eidx2         = (const int*)d_in[14];
    const float* etime2        = (const float*)d_in[15];

    const int N = 1024;
    const int NROWS = N + N * KNBR;  // 21504

    float* emb_all = (float*)d_ws;
    float* bias2_eff = emb_all + (size_t)NROWS * 128;
    unsigned short* wf1 = (unsigned short*)(bias2_eff + 256);
    unsigned short* wf2 = wf1 + 2 * WF1_PER_LAYER;

    setup_kernel<<<641, 256, 0, stream>>>(W1, W2, b2, time_b, wf1, wf2, bias2_eff);

    fused_mlp<false, 16><<<NROWS / 16, 256, 0, stream>>>(
        memory, edge_features, timestamps, time_w, time_b, source_nodes,
        nbr1, eidx1, etime1, nbr2, eidx2, etime2,
        emb_all, wf1, wf2, b1, bias2_eff, emb_all);

    fused_mlp<true, 8><<<N / 8, 256, 0, stream>>>(
        memory, edge_features, timestamps, time_w, time_b, source_nodes,
        nbr1, eidx1, etime1, nbr2, eidx2, etime2,
        emb_all, wf1 + WF1_PER_LAYER, wf2 + WF2_PER_LAYER,
        b1 + 128, bias2_eff + 128, (float*)d_out);
}

// Round 5
// 124.183 us; speedup vs baseline: 4.0007x; 1.1066x over previous
//
#include <hip/hip_runtime.h>
#include <hip/hip_bf16.h>
#include <math.h>

#define KNBR 20
#define NFK 384
#define NFPAD 392     // bf16 pad -> row stride 784B
#define CATPAD 264
#define KS1 12        // 384/32 k-steps
#define KS2 8         // 256/32 k-steps ("ones" block folded into bias2_eff)
#define WF1_PER_LAYER (8 * KS1 * 64 * 8)   // 49152
#define WF2_PER_LAYER (8 * KS2 * 64 * 8)   // 32768
#define INV2PI 0.15915494309189535f
#define NMEM_ELEMS 12800000                // 100000*128

typedef __attribute__((ext_vector_type(8))) short short8;
typedef __attribute__((ext_vector_type(4))) float f32x4;
typedef __attribute__((ext_vector_type(4))) unsigned short u16x4;

__device__ __forceinline__ unsigned short f2bf(float f) {
    unsigned u = __float_as_uint(f);
    unsigned r = (u + 0x7FFFu + ((u >> 16) & 1u)) >> 16;  // RNE
    return (unsigned short)r;
}
__device__ __forceinline__ float bf2f(unsigned short u) {
    return __uint_as_float((unsigned)u << 16);
}
__device__ __forceinline__ float fract_(float x) {
#if __has_builtin(__builtin_amdgcn_fractf)
    return __builtin_amdgcn_fractf(x);
#else
    return x - floorf(x);
#endif
}
__device__ __forceinline__ float cos_rev(float rev) {  // cos(2*pi*rev)
#if __has_builtin(__builtin_amdgcn_cosf)
    return __builtin_amdgcn_cosf(fract_(rev));
#else
    float o, r = fract_(rev);
    asm("v_cos_f32 %0, %1" : "=v"(o) : "v"(r));
    return o;
#endif
}
__device__ __forceinline__ f32x4 ldnt4(const float* p) {  // non-temporal 16B load
    return __builtin_nontemporal_load(reinterpret_cast<const f32x4*>(p));
}

// ---------------------------------------------------------------------------
// One-time setup: weight repack to MFMA B-frag order (bf16), ones-bias fold,
// and memory-table f32 -> bf16 conversion.
// Consumer reads: wf[(((ct*KS + ks)*64 + lane)*8 + j]
//   k = ks*32 + (lane>>4)*8 + j, col = ct*16 + (lane&15)
// ---------------------------------------------------------------------------
__global__ __launch_bounds__(256) void setup_kernel(
    const float* __restrict__ memory,
    const float* __restrict__ W1, const float* __restrict__ W2,
    const float* __restrict__ b2, const float* __restrict__ time_b,
    unsigned short* __restrict__ wf1, unsigned short* __restrict__ wf2,
    float* __restrict__ bias2_eff, unsigned short* __restrict__ memb)
{
    const int id = blockIdx.x * 256 + threadIdx.x;
    const int N1 = 2 * WF1_PER_LAYER;
    const int N2 = 2 * WF2_PER_LAYER;
    if (id < N1) {
        const int layer = id / WF1_PER_LAYER;
        const int idl = id % WF1_PER_LAYER;
        const int ct = idl / (KS1 * 512);
        const int ks = (idl / 512) % KS1;
        const int l = (idl >> 3) & 63;
        const int j = idl & 7;
        const int k = ks * 32 + (l >> 4) * 8 + j;
        const int col = ct * 16 + (l & 15);
        wf1[id] = f2bf(W1[(size_t)layer * NFK * 128 + k * 128 + col]);
    } else if (id < N1 + N2) {
        const int id2 = id - N1;
        const int layer = id2 / WF2_PER_LAYER;
        const int idl = id2 % WF2_PER_LAYER;
        const int ct = idl / (KS2 * 512);
        const int ks = (idl / 512) % KS2;
        const int l = (idl >> 3) & 63;
        const int j = idl & 7;
        const int k = ks * 32 + (l >> 4) * 8 + j;
        const int col = ct * 16 + (l & 15);
        wf2[id2] = f2bf(W2[(size_t)layer * NFK * 128 + k * 128 + col]);
    } else if (id < N1 + N2 + 256) {
        const int id3 = id - N1 - N2;
        const int layer = id3 / 128, col = id3 % 128;
        float s = b2[layer * 128 + col];
        for (int f = 0; f < 128; ++f)
            s += cosf(time_b[f]) * W2[(size_t)layer * NFK * 128 + (256 + f) * 128 + col];
        bias2_eff[id3] = s;
    } else {
        // memory table conversion: grid sized so cid covers [0, NMEM_ELEMS) exactly
        const size_t cid = (size_t)(id - (N1 + N2 + 256)) * 4;
        const f32x4 v = __builtin_nontemporal_load(
            reinterpret_cast<const f32x4*>(&memory[cid]));
        u16x4 o = { f2bf(v.x), f2bf(v.y), f2bf(v.z), f2bf(v.w) };
        __builtin_nontemporal_store(o, reinterpret_cast<u16x4*>(&memb[cid]));
    }
}

// ---------------------------------------------------------------------------
// Fused per-row MLP, 256 threads (4 waves), RPB rows/block.
// Layer-1 (!L2MODE, RPB=16): half-wave owns RPB/8 rows, full k range.
// Layer-2 (L2MODE, RPB=4): wave owns 1 row, k split 10/10 across lane-halves,
//   combined via __shfl_xor(.,32).
// Indices staged in LDS (coalesced once, broadcast-read).
// ---------------------------------------------------------------------------
template<bool L2MODE, int RPB>
__global__ __launch_bounds__(256) void fused_mlp(
    const unsigned short* __restrict__ memb,   // bf16 [100000,128]
    const float* __restrict__ edge_features,
    const float* __restrict__ timestamps,
    const float* __restrict__ time_w,
    const float* __restrict__ time_b,
    const int* __restrict__ source_nodes,
    const int* __restrict__ nbr1, const int* __restrict__ eidx1, const float* __restrict__ etime1,
    const int* __restrict__ nbr2, const int* __restrict__ eidx2, const float* __restrict__ etime2,
    const unsigned short* __restrict__ emb_all,  // bf16 [21504,128] = [conv ; embL1]
    const unsigned short* __restrict__ wf1,
    const unsigned short* __restrict__ wf2,
    const float* __restrict__ b1l,
    const float* __restrict__ bias2l,
    void* __restrict__ outv)
{
    __shared__ alignas(16) unsigned short nf[16][NFPAD];
    __shared__ alignas(16) unsigned short cat[16][CATPAD];
    __shared__ int   s_nbr[RPB][KNBR];
    __shared__ int   s_eix[RPB][KNBR];
    __shared__ float s_etm[RPB][KNBR];
    __shared__ float s_ts[RPB];
    __shared__ int   s_mid[RPB];

    const int tid = threadIdx.x;
    const int row0 = blockIdx.x * RPB;
    const int l32 = tid & 31;
    const int d4 = l32 * 4;

    // --- block-cooperative index staging (block-uniform source arrays) ---
    const int* nbr_src; const int* eix_src; const float* etm_src;
    if (L2MODE || row0 < 1024) {
        nbr_src = nbr1 + row0 * KNBR; eix_src = eidx1 + row0 * KNBR; etm_src = etime1 + row0 * KNBR;
    } else {
        const int i0 = row0 - 1024;
        nbr_src = nbr2 + i0 * KNBR; eix_src = eidx2 + i0 * KNBR; etm_src = etime2 + i0 * KNBR;
    }
    for (int i = tid; i < RPB * KNBR; i += 256) {
        (&s_nbr[0][0])[i] = nbr_src[i];
        (&s_eix[0][0])[i] = eix_src[i];
        (&s_etm[0][0])[i] = etm_src[i];
    }
    if (tid < RPB) {
        const int row = row0 + tid;
        float ts; int mid = 0;
        if (L2MODE) { ts = timestamps[row]; }
        else if (row0 < 1024) { ts = timestamps[row]; mid = source_nodes[row]; }
        else { const int i = row - 1024; ts = timestamps[i / KNBR]; mid = nbr1[i]; }
        s_ts[tid] = ts;
        s_mid[tid] = mid;
    }
    __syncthreads();

    const f32x4 twv = *reinterpret_cast<const f32x4*>(&time_w[d4]);
    const f32x4 tbv = *reinterpret_cast<const f32x4*>(&time_b[d4]);
    const f32x4 wtr = twv * INV2PI;
    const f32x4 btr = tbv * INV2PI;

    if constexpr (!L2MODE) {
        const int hw = tid >> 5;
        constexpr int RPH = RPB / 8;
#pragma unroll
        for (int ri = 0; ri < RPH; ++ri) {
            const int r = hw * RPH + ri;
            const float ts = s_ts[r];
            f32x4 am = {0,0,0,0}, ac = {0,0,0,0}, ae = {0,0,0,0};
#pragma unroll
            for (int k = 0; k < KNBR; ++k) {
                const int nid = s_nbr[r][k];
                const int eid = s_eix[r][k];
                const float dt = ts - s_etm[r][k];
                const float live = (nid != 0) ? 1.f : 0.f;
                const u16x4 mu = *reinterpret_cast<const u16x4*>(&memb[(size_t)nid * 128 + d4]);
                const f32x4 ev = ldnt4(&edge_features[(size_t)eid * 128 + d4]);
                am.x += live * bf2f(mu.x); am.y += live * bf2f(mu.y);
                am.z += live * bf2f(mu.z); am.w += live * bf2f(mu.w);
                ae += live * ev;
                ac.x += live * cos_rev(fmaf(dt, wtr.x, btr.x));
                ac.y += live * cos_rev(fmaf(dt, wtr.y, btr.y));
                ac.z += live * cos_rev(fmaf(dt, wtr.z, btr.z));
                ac.w += live * cos_rev(fmaf(dt, wtr.w, btr.w));
            }
            u16x4 pm = { f2bf(2.f*am.x), f2bf(2.f*am.y), f2bf(2.f*am.z), f2bf(2.f*am.w) };
            u16x4 pc = { f2bf(ac.x), f2bf(ac.y), f2bf(ac.z), f2bf(ac.w) };
            u16x4 pe = { f2bf(ae.x), f2bf(ae.y), f2bf(ae.z), f2bf(ae.w) };
            *reinterpret_cast<u16x4*>(&nf[r][d4])       = pm;
            *reinterpret_cast<u16x4*>(&nf[r][128 + d4]) = pc;
            *reinterpret_cast<u16x4*>(&nf[r][256 + d4]) = pe;
            const u16x4 md = *reinterpret_cast<const u16x4*>(&memb[(size_t)s_mid[r] * 128 + d4]);
            u16x4 pd = { f2bf(2.f*bf2f(md.x)), f2bf(2.f*bf2f(md.y)),
                         f2bf(2.f*bf2f(md.z)), f2bf(2.f*bf2f(md.w)) };
            *reinterpret_cast<u16x4*>(&cat[r][128 + d4]) = pd;
        }
    } else {
        const int r = tid >> 6;                  // wave id = row slot
        const int kbase = (tid & 32) ? (KNBR / 2) : 0;
        const int row = row0 + r;
        const float ts = s_ts[r];
        f32x4 am = {0,0,0,0}, ac = {0,0,0,0}, ae = {0,0,0,0};
#pragma unroll
        for (int kk = 0; kk < KNBR / 2; ++kk) {
            const int k = kbase + kk;
            const int nid = s_nbr[r][k];
            const int eid = s_eix[r][k];
            const float dt = ts - s_etm[r][k];
            const float live = (nid != 0) ? 1.f : 0.f;
            const u16x4 mu = *reinterpret_cast<const u16x4*>(
                &emb_all[(size_t)(1024 + row * KNBR + k) * 128 + d4]);
            const f32x4 ev = ldnt4(&edge_features[(size_t)eid * 128 + d4]);
            am.x += live * bf2f(mu.x); am.y += live * bf2f(mu.y);
            am.z += live * bf2f(mu.z); am.w += live * bf2f(mu.w);
            ae += live * ev;
            ac.x += live * cos_rev(fmaf(dt, wtr.x, btr.x));
            ac.y += live * cos_rev(fmaf(dt, wtr.y, btr.y));
            ac.z += live * cos_rev(fmaf(dt, wtr.z, btr.z));
            ac.w += live * cos_rev(fmaf(dt, wtr.w, btr.w));
        }
        // combine the two k-halves (lane ^ 32)
        am.x += __shfl_xor(am.x, 32); am.y += __shfl_xor(am.y, 32);
        am.z += __shfl_xor(am.z, 32); am.w += __shfl_xor(am.w, 32);
        ac.x += __shfl_xor(ac.x, 32); ac.y += __shfl_xor(ac.y, 32);
        ac.z += __shfl_xor(ac.z, 32); ac.w += __shfl_xor(ac.w, 32);
        ae.x += __shfl_xor(ae.x, 32); ae.y += __shfl_xor(ae.y, 32);
        ae.z += __shfl_xor(ae.z, 32); ae.w += __shfl_xor(ae.w, 32);
        if (!(tid & 32)) {
            u16x4 pm = { f2bf(am.x), f2bf(am.y), f2bf(am.z), f2bf(am.w) };
            u16x4 pc = { f2bf(ac.x), f2bf(ac.y), f2bf(ac.z), f2bf(ac.w) };
            u16x4 pe = { f2bf(ae.x), f2bf(ae.y), f2bf(ae.z), f2bf(ae.w) };
            *reinterpret_cast<u16x4*>(&nf[r][d4])       = pm;
            *reinterpret_cast<u16x4*>(&nf[r][128 + d4]) = pc;
            *reinterpret_cast<u16x4*>(&nf[r][256 + d4]) = pe;
            // mid = conv row (already bf16, scale 1): raw copy
            *reinterpret_cast<u16x4*>(&cat[r][128 + d4]) =
                *reinterpret_cast<const u16x4*>(&emb_all[(size_t)row * 128 + d4]);
        }
    }
    __syncthreads();

    const int lane = tid & 63;
    const int wv = tid >> 6;
    const int lo = lane & 15, hi = lane >> 4;

    // ---- GEMM1: s = relu(nf @ W1 + 20*b1) ----
    f32x4 acc[2];
    acc[0] = (f32x4){0.f,0.f,0.f,0.f}; acc[1] = (f32x4){0.f,0.f,0.f,0.f};
    for (int ks = 0; ks < KS1; ++ks) {
        const short8 a = *reinterpret_cast<const short8*>(&nf[lo][ks * 32 + hi * 8]);
#pragma unroll
        for (int c = 0; c < 2; ++c) {
            const int ct = wv * 2 + c;
            const short8 b = *reinterpret_cast<const short8*>(
                &wf1[(((size_t)ct * KS1 + ks) * 64 + lane) * 8]);
            acc[c] = __builtin_amdgcn_mfma_f32_16x16x32_bf16(a, b, acc[c], 0, 0, 0);
        }
    }
#pragma unroll
    for (int c = 0; c < 2; ++c) {
        const int col = (wv * 2 + c) * 16 + lo;
        const float bv = 20.f * b1l[col];
#pragma unroll
        for (int j = 0; j < 4; ++j) {
            const int r = hi * 4 + j;              // C layout: col=lane&15, row=(lane>>4)*4+j
            if (RPB == 16 || r < RPB)
                cat[r][col] = f2bf(fmaxf(acc[c][j] + bv, 0.f));
        }
    }
    __syncthreads();

    // ---- GEMM2: out = cat @ W2[0:256] + bias2_eff ----
    acc[0] = (f32x4){0.f,0.f,0.f,0.f}; acc[1] = (f32x4){0.f,0.f,0.f,0.f};
    for (int ks = 0; ks < KS2; ++ks) {
        const short8 a = *reinterpret_cast<const short8*>(&cat[lo][ks * 32 + hi * 8]);
#pragma unroll
        for (int c = 0; c < 2; ++c) {
            const int ct = wv * 2 + c;
            const short8 b = *reinterpret_cast<const short8*>(
                &wf2[(((size_t)ct * KS2 + ks) * 64 + lane) * 8]);
            acc[c] = __builtin_amdgcn_mfma_f32_16x16x32_bf16(a, b, acc[c], 0, 0, 0);
        }
    }
#pragma unroll
    for (int c = 0; c < 2; ++c) {
        const int col = (wv * 2 + c) * 16 + lo;
        const float bv = bias2l[col];
#pragma unroll
        for (int j = 0; j < 4; ++j) {
            const int r = hi * 4 + j;
            if (RPB == 16 || r < RPB) {
                if constexpr (L2MODE)
                    ((float*)outv)[(size_t)(row0 + r) * 128 + col] = acc[c][j] + bv;
                else
                    ((unsigned short*)outv)[(size_t)(row0 + r) * 128 + col] = f2bf(acc[c][j] + bv);
            }
        }
    }
}

// ---------------------------------------------------------------------------
extern "C" void kernel_launch(void* const* d_in, const int* in_sizes, int n_in,
                              void* d_out, int out_size, void* d_ws, size_t ws_size,
                              hipStream_t stream) {
    const float* memory        = (const float*)d_in[0];
    const float* edge_features = (const float*)d_in[1];
    const float* timestamps    = (const float*)d_in[2];
    const float* time_w        = (const float*)d_in[3];
    const float* time_b        = (const float*)d_in[4];
    const float* W1            = (const float*)d_in[5];
    const float* b1            = (const float*)d_in[6];
    const float* W2            = (const float*)d_in[7];
    const float* b2            = (const float*)d_in[8];
    const int*   source_nodes  = (const int*)d_in[9];
    const int*   nbr1          = (const int*)d_in[10];
    const int*   eidx1         = (const int*)d_in[11];
    const float* etime1        = (const float*)d_in[12];
    const int*   nbr2          = (const int*)d_in[13];
    const int*   eidx2         = (const int*)d_in[14];
    const float* etime2        = (const float*)d_in[15];

    const int N = 1024;
    const int NROWS = N + N * KNBR;  // 21504

    // ws: memb bf16 [12.8M] | emb_all bf16 [21504*128] | bias2_eff [256 f32] | wf1 | wf2
    unsigned short* memb = (unsigned short*)d_ws;
    unsigned short* emb_all = memb + NMEM_ELEMS;
    float* bias2_eff = (float*)(emb_all + (size_t)NROWS * 128);
    unsigned short* wf1 = (unsigned short*)(bias2_eff + 256);
    unsigned short* wf2 = wf1 + 2 * WF1_PER_LAYER;

    // setup ids: 164096 (= 641*256) for wf/bias + 3.2M for mem conversion
    setup_kernel<<<641 + NMEM_ELEMS / 4 / 256, 256, 0, stream>>>(
        memory, W1, W2, b2, time_b, wf1, wf2, bias2_eff, memb);

    fused_mlp<false, 16><<<NROWS / 16, 256, 0, stream>>>(
        memb, edge_features, timestamps, time_w, time_b, source_nodes,
        nbr1, eidx1, etime1, nbr2, eidx2, etime2,
        emb_all, wf1, wf2, b1, bias2_eff, emb_all);

    fused_mlp<true, 4><<<N / 4, 256, 0, stream>>>(
        memb, edge_features, timestamps, time_w, time_b, source_nodes,
        nbr1, eidx1, etime1, nbr2, eidx2, etime2,
        emb_all, wf1 + WF1_PER_LAYER, wf2 + WF2_PER_LAYER,
        b1 + 128, bias2_eff + 128, (float*)d_out);
}